// Round 1
// baseline (111.507 us; speedup 1.0000x reference)
//
#include <hip/hip_runtime.h>
#include <hip/hip_bf16.h>
#include <stdint.h>
#include <stddef.h>

#define TM 16      // output rows per block
#define CIN 64     // C_in
#define NK3 27     // K3 neighbors
#define NK3P 28    // padded to multiple of 4 (kc=27 contributes zero)
#define COUT 128   // C_out
#define EPS_LN 1e-3f
#define KCH  (NK3 * CIN / 32)    // 54 real k-chunks of 32
#define KCHP (NK3P * CIN / 32)   // 56 padded k-chunks
#define NT   (COUT / 16)         // 8 column tiles (one per wave)
#define NSLAB (NK3P / 4)         // 7 K-loop iterations of 4 kc each (was 14 of 2)
#define PK_BYTES (NT * KCHP * 64 * 8 * 2)   // 458752

typedef __attribute__((ext_vector_type(8))) short   short8;   // MFMA A/B frag (8 bf16)
typedef __attribute__((ext_vector_type(4))) float   floatx4;  // MFMA C/D frag
typedef __attribute__((ext_vector_type(4))) unsigned short ushort4v;

__device__ __forceinline__ unsigned short f2b(float f) {
    union { float f; unsigned int i; } v;
    v.f = f;
    unsigned int i = v.i; // RNE bf16
    return (unsigned short)((i + 0x7fffu + ((i >> 16) & 1u)) >> 16);
}

// ---- kernel 1: pack W -> bf16 B-fragments, coalesced via LDS transpose ----
// One block per k-chunk kk (56 blocks). Loads the 32x128 fp32 W-slab with
// fully-coalesced float4 (replaces the old stride-512B scalar loads that
// generated 229k separate 64B-line transactions at 1.75 waves/CU), then
// emits the 512 short8 fragments from LDS (+1-col pad -> <=2-way bank
// aliasing on the transpose reads, which is free on CDNA4).
__global__ __launch_bounds__(256) void pack_w(const float* __restrict__ Wm,
                                              const int* __restrict__ voxel_idx,
                                              const int* __restrict__ num_list,
                                              int Bc,
                                              unsigned short* __restrict__ pk,
                                              int* __restrict__ flags) {
    __shared__ float s_w[32][COUT + 1];   // 32 K-rows x 128 cols (+1 pad)
    const int t  = threadIdx.x;
    const int kk = blockIdx.x;            // 0..KCHP-1

    // one-time dtype probe (unchanged)
    if (kk == 0 && t < 64) {
        int wv = voxel_idx[2 * t + 1];
        unsigned long long nz = __ballot(wv != 0);
        if (t == 0) {
            int f = (nz == 0ULL) ? 1 : 0;     // int64 voxel_idx -> odd words all zero
            bool n64 = false;
            if (Bc >= 2) {
                n64 = (num_list[1] == 0) && (num_list[0] != 0);
                if (Bc >= 4) n64 = n64 && (num_list[3] == 0);
            }
            if (n64) f |= 2;
            flags[0] = f;
        }
    }

    if (kk < KCH) {
        #pragma unroll
        for (int i = 0; i < 4; ++i) {
            int s   = t + i * 256;        // float4 slot 0..1023
            int row = s >> 5;             // 32 float4 per row
            int c4  = (s & 31) * 4;
            float4 v = *(const float4*)(Wm + (size_t)(kk * 32 + row) * COUT + c4);
            s_w[row][c4 + 0] = v.x; s_w[row][c4 + 1] = v.y;
            s_w[row][c4 + 2] = v.z; s_w[row][c4 + 3] = v.w;
        }
    }
    __syncthreads();

    #pragma unroll
    for (int i = 0; i < 2; ++i) {
        int slot = t + i * 256;           // 0..511 = nt*64 + lane
        int l  = slot & 63;
        int nt = slot >> 6;
        int q  = l >> 4, n = l & 15;
        short8 v = {0, 0, 0, 0, 0, 0, 0, 0};
        if (kk < KCH) {                   // kk 54/55 emit zero pad fragments
            #pragma unroll
            for (int j = 0; j < 8; ++j)
                v[j] = (short)f2b(s_w[q * 8 + j][nt * 16 + n]);
        }
        *(short8*)(pk + ((size_t)(nt * KCHP + kk) * 64 + l) * 8) = v;
    }
}

// ---- kernel 2: gather + MFMA + fused LN/ReLU ----
// Same proven structure, but the K-loop now processes 4 kc per iteration
// (7 iterations instead of 14) -> half the full-block barrier drains, which
// model says is the main serial overhead. Prefetch discipline unchanged:
// gathers 2 slabs ahead, low-half B fragments 1 slab ahead across the sync,
// high-half B loaded in-body under the first 4 MFMAs (L2-resident pk).
__global__ __launch_bounds__(512) void dpc_mfma(
    const float* __restrict__ features,   // fp32 [N][CIN]
    const float* __restrict__ center,     // fp32 [M][3]
    const int* __restrict__ voxel_idx,    // int32/int64 (flags)
    const int* __restrict__ num_list,     // int32/int64 (flags)
    const unsigned short* __restrict__ pk,
    const int* __restrict__ flags,
    const float* __restrict__ gamma_,
    const float* __restrict__ beta_,
    float* __restrict__ out_feat,         // fp32 [Rtot][COUT]
    float* __restrict__ out_coor,         // fp32 [Rtot][4]
    int N, int M, int B, int K, int Rtot)
{
    __shared__ int s_vid[TM][NK3P];
    __shared__ int s_src[TM];
    __shared__ int s_valid[TM];
    __shared__ __align__(16) unsigned short s_a[3][4096]; // tri-buffer, 4-kc slabs (8KB each)
    __shared__ float s_c[TM][COUT + 4];

    const int t  = threadIdx.x;
    const int R0 = blockIdx.x * TM;

    const int fl = flags[0];              // uniform scalar load
    const bool vidx64 = (fl & 1) != 0;
    const bool nl64   = (fl & 2) != 0;

    // ---- preamble: per-row source index + validity ----
    if (t < TM) {
        int r = R0 + t;
        int src = 0, valid = 0;
        if (r < Rtot) {
            int b = r / K;
            int j = r - b * K;
            int offs = 0, nlb = 0;
            for (int i = 0; i < B; ++i) {
                int v = nl64 ? num_list[2 * i] : num_list[i];
                if (i < b) offs += v;
                if (i == b) nlb = v;
            }
            int end = nlb < K ? nlb : K;
            valid = (j < end) ? 1 : 0;
            src = offs + j;
            if (src < 0) src = 0;
            if (src > M - 1) src = M - 1;
        }
        s_src[t] = src;
        s_valid[t] = valid;
    }
    __syncthreads();

    // ---- coords output ----
    if (t < TM * 4) {
        int i = t >> 2, comp = t & 3;
        int r = R0 + i;
        if (r < Rtot) {
            float val;
            if (comp == 0) {
                int b = r / K;
                val = (b < B - 1) ? (float)(b + 1) : 0.0f;
            } else {
                val = s_valid[i] ? center[(size_t)s_src[i] * 3 + comp - 1] : 0.0f;
            }
            out_coor[(size_t)r * 4 + comp] = val;
        }
    }

    // ---- stage voxel ids (pad kc=27 with -1 -> zero A fragment) ----
    for (int lin = t; lin < TM * NK3P; lin += 512) {
        int i = lin / NK3P;
        int k = lin - i * NK3P;
        int v = -1;
        if (k < NK3) {
            size_t e = (size_t)s_src[i] * NK3 + k;
            v = vidx64 ? voxel_idx[2 * e] : voxel_idx[e];
        }
        s_vid[i][k] = v;
    }
    __syncthreads();

    // ---- staging geometry: thread t stages TWO float4s per slab:
    //      kc-in-slab sub0 (0/1) and sub0+2, same (row m, col c0) ----
    const int sub0  = t >> 8;             // 0/1
    const int rem   = t & 255;
    const int m     = rem >> 4;           // row 0..15
    const int c0    = (rem & 15) * 4;     // cin col base
    const int chunk = c0 >> 5;
    const int q4    = (c0 & 31) >> 3;
    const int j0    = c0 & 7;
    // slab layout (shorts): kc*1024 + chunk*512 + (q4*16+m)*8 + j0
    // so MFMA j (=kc*2+chunk) reads contiguously at j*512 + lane*8
    const int aoffA = sub0 * 1024 + chunk * 512 + (q4 * 16 + m) * 8 + j0;

    auto gatherOne = [&](int kc) -> float4 {
        int idx = s_vid[m][kc];
        float4 r = make_float4(0.f, 0.f, 0.f, 0.f);
        if (idx >= 0) {
            if (idx > N - 1) idx = N - 1;
            r = *(const float4*)(features + (size_t)idx * CIN + c0);
        }
        return r;
    };
    auto stash = [&](int buf, float4 vA, float4 vB) {
        ushort4v u;
        u[0] = f2b(vA.x); u[1] = f2b(vA.y); u[2] = f2b(vA.z); u[3] = f2b(vA.w);
        *(ushort4v*)&s_a[buf][aoffA] = u;
        u[0] = f2b(vB.x); u[1] = f2b(vB.y); u[2] = f2b(vB.z); u[3] = f2b(vB.w);
        *(ushort4v*)&s_a[buf][aoffA + 2048] = u;
    };

    const int w    = t >> 6;              // wave 0..7 -> col tile nt = w
    const int lane = t & 63;
    auto loadB = [&](int kk) -> short8 {
        return *(const short8*)(pk + ((size_t)(w * KCHP + kk) * 64 + lane) * 8);
    };

    floatx4 acc = {0.f, 0.f, 0.f, 0.f};

    // ---- prologue: slab0 -> buf0; slab1 -> regs; B(kk 0..3) -> regs ----
    float4 p0  = gatherOne(sub0),     p1  = gatherOne(sub0 + 2);
    float4 cA0 = gatherOne(4 + sub0), cA1 = gatherOne(4 + sub0 + 2);
    short8 bb0 = loadB(0), bb1 = loadB(1), bb2 = loadB(2), bb3 = loadB(3);
    stash(0, p0, p1);
    __syncthreads();

    for (int q = 0; q < NSLAB; ++q) {
        const bool hasC = (q + 1 < NSLAB);
        const bool hasN = (q + 2 < NSLAB);

        float4 nA0, nA1;
        if (hasN) {                                  // drained 2 bodies later
            nA0 = gatherOne(4 * (q + 2) + sub0);
            nA1 = gatherOne(4 * (q + 2) + sub0 + 2);
        }
        const int kb = 8 * q;
        short8 bb4 = loadB(kb + 4), bb5 = loadB(kb + 5),
               bb6 = loadB(kb + 6), bb7 = loadB(kb + 7);   // hidden under MFMAs 0..3
        short8 nb0, nb1, nb2, nb3;
        if (hasC) {
            nb0 = loadB(kb + 8);  nb1 = loadB(kb + 9);
            nb2 = loadB(kb + 10); nb3 = loadB(kb + 11);
        }

        const int buf = q % 3;
        const unsigned short* sa = &s_a[buf][0];
        const short8 a0 = *(const short8*)&sa[       lane * 8];
        const short8 a1 = *(const short8*)&sa[ 512 + lane * 8];
        const short8 a2 = *(const short8*)&sa[1024 + lane * 8];
        const short8 a3 = *(const short8*)&sa[1536 + lane * 8];
        acc = __builtin_amdgcn_mfma_f32_16x16x32_bf16(a0, bb0, acc, 0, 0, 0);
        acc = __builtin_amdgcn_mfma_f32_16x16x32_bf16(a1, bb1, acc, 0, 0, 0);
        acc = __builtin_amdgcn_mfma_f32_16x16x32_bf16(a2, bb2, acc, 0, 0, 0);
        acc = __builtin_amdgcn_mfma_f32_16x16x32_bf16(a3, bb3, acc, 0, 0, 0);
        const short8 a4 = *(const short8*)&sa[2048 + lane * 8];
        const short8 a5 = *(const short8*)&sa[2560 + lane * 8];
        const short8 a6 = *(const short8*)&sa[3072 + lane * 8];
        const short8 a7 = *(const short8*)&sa[3584 + lane * 8];
        acc = __builtin_amdgcn_mfma_f32_16x16x32_bf16(a4, bb4, acc, 0, 0, 0);
        acc = __builtin_amdgcn_mfma_f32_16x16x32_bf16(a5, bb5, acc, 0, 0, 0);
        acc = __builtin_amdgcn_mfma_f32_16x16x32_bf16(a6, bb6, acc, 0, 0, 0);
        acc = __builtin_amdgcn_mfma_f32_16x16x32_bf16(a7, bb7, acc, 0, 0, 0);

        if (hasC) stash((q + 1) % 3, cA0, cA1);
        __syncthreads();
        if (hasC) { bb0 = nb0; bb1 = nb1; bb2 = nb2; bb3 = nb3; }
        if (hasN) { cA0 = nA0; cA1 = nA1; }
    }

    // ---- C -> LDS (C/D layout: col=lane&15, row=(lane>>4)*4+reg) ----
    {
        const int cq = lane >> 4, n = lane & 15;
        #pragma unroll
        for (int reg = 0; reg < 4; ++reg)
            s_c[cq * 4 + reg][w * 16 + n] = acc[reg];
    }
    __syncthreads();

    // ---- fused LayerNorm + ReLU epilogue (2 rows per wave) ----
    const int c2 = lane * 2;
    const float g0  = gamma_[c2];
    const float g1  = gamma_[c2 + 1];
    const float be0 = beta_[c2];
    const float be1 = beta_[c2 + 1];

    #pragma unroll
    for (int i = 0; i < 2; ++i) {
        int row = w * 2 + i;
        float a0 = s_c[row][c2];
        float a1 = s_c[row][c2 + 1];
        float s  = a0 + a1;
        float ss = a0 * a0 + a1 * a1;
        #pragma unroll
        for (int mm = 1; mm < 64; mm <<= 1) {
            s  += __shfl_xor(s,  mm, 64);
            ss += __shfl_xor(ss, mm, 64);
        }
        float mu   = s * (1.0f / COUT);
        float var  = ss * (1.0f / COUT) - mu * mu;
        float rstd = rsqrtf(var + EPS_LN);
        float v0 = (a0 - mu) * rstd * g0 + be0;
        float v1 = (a1 - mu) * rstd * g1 + be1;
        v0 = fmaxf(v0, 0.f);
        v1 = fmaxf(v1, 0.f);
        if (!s_valid[row]) { v0 = 0.f; v1 = 0.f; }
        int r = R0 + row;
        if (r < Rtot) {
            out_feat[(size_t)r * COUT + c2]     = v0;
            out_feat[(size_t)r * COUT + c2 + 1] = v1;
        }
    }
}

extern "C" void kernel_launch(void* const* d_in, const int* in_sizes, int n_in,
                              void* d_out, int out_size, void* d_ws, size_t ws_size,
                              hipStream_t stream) {
    const float* features = (const float*)d_in[0];
    const float* center   = (const float*)d_in[1];
    const int*   vidx     = (const int*)d_in[2];
    const int*   num_list = (const int*)d_in[3];
    const float* Wm       = (const float*)d_in[4];
    const float* gamma_   = (const float*)d_in[5];
    const float* beta_    = (const float*)d_in[6];

    const int B    = in_sizes[3];                 // 4
    const int Cout = in_sizes[5];                 // 128
    const int M    = in_sizes[1] / 3;             // 40000
    const int K3v  = in_sizes[2] / M;             // 27
    const int Cin  = (in_sizes[4] / Cout) / K3v;  // 64
    const int N    = in_sizes[0] / Cin;           // 200000
    const int Rtot = out_size / (Cout + 4);       // 8192
    const int K    = Rtot / B;                    // 2048

    float* out_feat = (float*)d_out;
    float* out_coor = out_feat + (size_t)Rtot * Cout;

    unsigned short* pk = (unsigned short*)d_ws;
    int* flags = (int*)((char*)d_ws + PK_BYTES);

    pack_w<<<dim3(KCHP), dim3(256), 0, stream>>>(Wm, vidx, num_list, B, pk, flags);

    const int tiles = (Rtot + TM - 1) / TM;             // 512
    dpc_mfma<<<dim3(tiles), dim3(512), 0, stream>>>(
        features, center, vidx, num_list, pk, flags, gamma_, beta_,
        out_feat, out_coor, N, M, B, K, Rtot);
}